// Round 1
// baseline (395.736 us; speedup 1.0000x reference)
//
#include <hip/hip_runtime.h>
#include <stdint.h>

#define BB 8
#define LL 2048
#define DT 32
#define HID 544
#define REGP 5.0f
#define BETA0 0.4f
#define BETA1 0.3f
#define EPSV 1e-6f

typedef float v4f __attribute__((ext_vector_type(4)));

// Kernel A: per-row (b,i): hidden_vector (544 f32) + 4 fused dot-product
// scalars into ws (biases folded; gate side pre-scaled by -REG).
__global__ __launch_bounds__(256) void prep_k(
    const int* __restrict__ etype, const float* __restrict__ etime,
    const float* __restrict__ wtpos, const float* __restrict__ temb,
    const float* __restrict__ wl, const float* __restrict__ wg,
    const float* __restrict__ blp, const float* __restrict__ bgp,
    float* __restrict__ hidden,
    float* __restrict__ pa, float* __restrict__ pbl,
    float* __restrict__ ga5, float* __restrict__ gb5)
{
    const int row = blockIdx.x;          // b*L + i
    const int i = row & (LL - 1);
    const int tid = threadIdx.x;
    const float t = etime[row];

    // div_term[k] = exp(-k * ln(10000)/256), k in [0,256)
    const float c = -0.03597789207803197f;   // -ln(10000)/256
    float divt = expf((float)tid * c);
    float arc = fmaf((float)i, divt, t * wtpos[tid]);
    size_t hbase = (size_t)row * HID;
    __builtin_nontemporal_store(sinf(arc), hidden + hbase + tid);
    __builtin_nontemporal_store(cosf(arc), hidden + hbase + 256 + tid);

    if (tid < 32) {
        int ty = etype[row];
        float te = temb[ty * DT + tid];
        __builtin_nontemporal_store(te, hidden + hbase + 512 + tid);
        float va = te * wl[tid];
        float vb = te * wl[32 + tid];
        float vc = te * wg[tid];
        float vd = te * wg[32 + tid];
        #pragma unroll
        for (int m = 16; m > 0; m >>= 1) {
            va += __shfl_xor(va, m, 64);
            vb += __shfl_xor(vb, m, 64);
            vc += __shfl_xor(vc, m, 64);
            vd += __shfl_xor(vd, m, 64);
        }
        if (tid == 0) {
            pa[row]  = va;                       // j-side lengthscale
            pbl[row] = vb + blp[0];              // i-side lengthscale + bias
            ga5[row] = -REGP * vc;               // j-side gate, pre-scaled
            gb5[row] = -REGP * (vd + bgp[0]);    // i-side gate + bias, scaled
        }
    }
}

// Kernel B: scores + t_diff (f32). Grid (i-tile, b); 256 threads own a FULL
// row (8 consecutive j each -> 2x float4 nontemporal stores per stream),
// looping over 8 i rows reusing j-side registers.
__global__ __launch_bounds__(256) void pair_k(
    const float* __restrict__ etime,
    const float* __restrict__ pa, const float* __restrict__ pbl,
    const float* __restrict__ ga5, const float* __restrict__ gb5,
    float* __restrict__ scores, float* __restrict__ tdiff)
{
    const int b  = blockIdx.y;
    const int i0 = blockIdx.x << 3;
    const int j0 = threadIdx.x << 3;     // 8 consecutive j per thread
    const int rowb = b * LL;

    const v4f tjA = *(const v4f*)(etime + rowb + j0);
    const v4f tjB = *(const v4f*)(etime + rowb + j0 + 4);
    const v4f pjA = *(const v4f*)(pa + rowb + j0);
    const v4f pjB = *(const v4f*)(pa + rowb + j0 + 4);
    const v4f gjA = *(const v4f*)(ga5 + rowb + j0);
    const v4f gjB = *(const v4f*)(ga5 + rowb + j0 + 4);

    const float tjv[8] = {tjA.x, tjA.y, tjA.z, tjA.w, tjB.x, tjB.y, tjB.z, tjB.w};
    const float pjv[8] = {pjA.x, pjA.y, pjA.z, pjA.w, pjB.x, pjB.y, pjB.z, pjB.w};
    const float gjv[8] = {gjA.x, gjA.y, gjA.z, gjA.w, gjB.x, gjB.y, gjB.z, gjB.w};

    #pragma unroll
    for (int ii = 0; ii < 8; ++ii) {
        const int i = i0 + ii;
        const float ti  = etime[rowb + i];
        const float pbi = pbl[rowb + i];
        const float gbi = gb5[rowb + i];
        const size_t base = ((size_t)(rowb + i) << 11) + j0;

        float dd[8];
        #pragma unroll
        for (int e = 0; e < 8; ++e) dd[e] = fabsf(tjv[e] - ti);

        v4f d0 = {dd[0], dd[1], dd[2], dd[3]};
        v4f d1 = {dd[4], dd[5], dd[6], dd[7]};
        __builtin_nontemporal_store(d0, (v4f*)(tdiff + base));
        __builtin_nontemporal_store(d1, (v4f*)(tdiff + base + 4));

        float sc[8];
        if (j0 < i) {
            #pragma unroll
            for (int e = 0; e < 8; ++e) {
                float l  = __logf(1.0f + __expf(pjv[e] + pbi)) + EPSV;
                float rl = __builtin_amdgcn_rcpf(l);
                float u  = dd[e] * rl;
                float kse = __expf(-0.5f * u * u);
                float kex = __expf(-u);
                float g   = __builtin_amdgcn_rcpf(1.0f + __expf(gjv[e] + gbi));
                float v   = g * fmaf(BETA0, kse, BETA1 * kex);
                sc[e] = ((j0 + e) < i) ? v : 0.0f;
            }
        } else {
            #pragma unroll
            for (int e = 0; e < 8; ++e) sc[e] = 0.0f;
        }
        v4f s0 = {sc[0], sc[1], sc[2], sc[3]};
        v4f s1 = {sc[4], sc[5], sc[6], sc[7]};
        __builtin_nontemporal_store(s0, (v4f*)(scores + base));
        __builtin_nontemporal_store(s1, (v4f*)(scores + base + 4));
    }
}

extern "C" void kernel_launch(void* const* d_in, const int* in_sizes, int n_in,
                              void* d_out, int out_size, void* d_ws, size_t ws_size,
                              hipStream_t stream) {
    const int*   etype = (const int*)d_in[0];
    const float* etime = (const float*)d_in[1];
    // d_in[2] arrival_times: unused by the reference
    const float* wtpos = (const float*)d_in[3];
    const float* temb  = (const float*)d_in[4];
    const float* wl    = (const float*)d_in[5];
    const float* blp   = (const float*)d_in[6];
    const float* wg    = (const float*)d_in[7];
    const float* bgp   = (const float*)d_in[8];

    float* out    = (float*)d_out;
    float* scores = out;                                  // [8,2048,2048]
    float* hidden = out + (size_t)BB * LL * LL;           // [8,2048,544]
    float* tdiff  = hidden + (size_t)BB * LL * HID;       // [8,2048,2048]

    float* pa  = (float*)d_ws;
    float* pbl = pa + BB * LL;
    float* ga5 = pbl + BB * LL;
    float* gb5 = ga5 + BB * LL;

    prep_k<<<BB * LL, 256, 0, stream>>>(etype, etime, wtpos, temb, wl, wg,
                                        blp, bgp, hidden, pa, pbl, ga5, gb5);
    pair_k<<<dim3(LL / 8, BB), 256, 0, stream>>>(etime, pa, pbl, ga5, gb5,
                                                 scores, tdiff);
}

// Round 2
// 328.643 us; speedup vs baseline: 1.2042x; 1.2042x over previous
//
#include <hip/hip_runtime.h>
#include <stdint.h>

#define BB 8
#define LL 2048
#define DT 32
#define HID 544
#define REGP 5.0f
#define BETA0 0.4f
#define BETA1 0.3f
#define EPSV 1e-6f

typedef float v4f __attribute__((ext_vector_type(4)));

// Kernel A: per-row (b,i): hidden_vector (544 f32) + 4 fused dot-product
// scalars into ws (biases folded; gate side pre-scaled by -REG).
__global__ __launch_bounds__(256) void prep_k(
    const int* __restrict__ etype, const float* __restrict__ etime,
    const float* __restrict__ wtpos, const float* __restrict__ temb,
    const float* __restrict__ wl, const float* __restrict__ wg,
    const float* __restrict__ blp, const float* __restrict__ bgp,
    float* __restrict__ hidden,
    float* __restrict__ pa, float* __restrict__ pbl,
    float* __restrict__ ga5, float* __restrict__ gb5)
{
    const int row = blockIdx.x;          // b*L + i
    const int i = row & (LL - 1);
    const int tid = threadIdx.x;
    const float t = etime[row];

    // div_term[k] = exp(-k * ln(10000)/256), k in [0,256)
    const float c = -0.03597789207803197f;   // -ln(10000)/256
    float divt = expf((float)tid * c);
    float arc = fmaf((float)i, divt, t * wtpos[tid]);
    size_t hbase = (size_t)row * HID;
    __builtin_nontemporal_store(sinf(arc), hidden + hbase + tid);
    __builtin_nontemporal_store(cosf(arc), hidden + hbase + 256 + tid);

    if (tid < 32) {
        int ty = etype[row];
        float te = temb[ty * DT + tid];
        __builtin_nontemporal_store(te, hidden + hbase + 512 + tid);
        float va = te * wl[tid];
        float vb = te * wl[32 + tid];
        float vc = te * wg[tid];
        float vd = te * wg[32 + tid];
        #pragma unroll
        for (int m = 16; m > 0; m >>= 1) {
            va += __shfl_xor(va, m, 64);
            vb += __shfl_xor(vb, m, 64);
            vc += __shfl_xor(vc, m, 64);
            vd += __shfl_xor(vd, m, 64);
        }
        if (tid == 0) {
            pa[row]  = va;                       // j-side lengthscale
            pbl[row] = vb + blp[0];              // i-side lengthscale + bias
            ga5[row] = -REGP * vc;               // j-side gate, pre-scaled
            gb5[row] = -REGP * (vd + bgp[0]);    // i-side gate + bias, scaled
        }
    }
}

// Kernel B: scores + t_diff (f32). Grid (j-half, i-tile, b); 256 threads,
// each thread owns 4 CONSECUTIVE j (wave store = 1024 contiguous bytes,
// fully dense lines -> nontemporal streams cleanly), loops over 8 i rows
// reusing j-side registers.
__global__ __launch_bounds__(256) void pair_k(
    const float* __restrict__ etime,
    const float* __restrict__ pa, const float* __restrict__ pbl,
    const float* __restrict__ ga5, const float* __restrict__ gb5,
    float* __restrict__ scores, float* __restrict__ tdiff)
{
    const int b  = blockIdx.z;
    const int i0 = blockIdx.y << 3;
    const int j0 = (blockIdx.x << 10) + (threadIdx.x << 2);
    const int rowb = b * LL;

    const v4f tj = *(const v4f*)(etime + rowb + j0);
    const v4f pj = *(const v4f*)(pa + rowb + j0);
    const v4f gj = *(const v4f*)(ga5 + rowb + j0);
    const float tjv[4] = {tj.x, tj.y, tj.z, tj.w};
    const float pjv[4] = {pj.x, pj.y, pj.z, pj.w};
    const float gjv[4] = {gj.x, gj.y, gj.z, gj.w};

    #pragma unroll
    for (int ii = 0; ii < 8; ++ii) {
        const int i = i0 + ii;
        const float ti  = etime[rowb + i];
        const float pbi = pbl[rowb + i];
        const float gbi = gb5[rowb + i];
        const size_t base = ((size_t)(rowb + i) << 11) + j0;

        float dd[4];
        #pragma unroll
        for (int e = 0; e < 4; ++e) dd[e] = fabsf(tjv[e] - ti);
        v4f dv = {dd[0], dd[1], dd[2], dd[3]};
        __builtin_nontemporal_store(dv, (v4f*)(tdiff + base));

        float s[4];
        if (j0 < i) {
            #pragma unroll
            for (int e = 0; e < 4; ++e) {
                float l  = __logf(1.0f + __expf(pjv[e] + pbi)) + EPSV;
                float rl = __builtin_amdgcn_rcpf(l);
                float u  = dd[e] * rl;
                float kse = __expf(-0.5f * u * u);
                float kex = __expf(-u);
                float g   = __builtin_amdgcn_rcpf(1.0f + __expf(gjv[e] + gbi));
                float v   = g * fmaf(BETA0, kse, BETA1 * kex);
                s[e] = ((j0 + e) < i) ? v : 0.0f;
            }
        } else {
            #pragma unroll
            for (int e = 0; e < 4; ++e) s[e] = 0.0f;
        }
        v4f sv = {s[0], s[1], s[2], s[3]};
        __builtin_nontemporal_store(sv, (v4f*)(scores + base));
    }
}

extern "C" void kernel_launch(void* const* d_in, const int* in_sizes, int n_in,
                              void* d_out, int out_size, void* d_ws, size_t ws_size,
                              hipStream_t stream) {
    const int*   etype = (const int*)d_in[0];
    const float* etime = (const float*)d_in[1];
    // d_in[2] arrival_times: unused by the reference
    const float* wtpos = (const float*)d_in[3];
    const float* temb  = (const float*)d_in[4];
    const float* wl    = (const float*)d_in[5];
    const float* blp   = (const float*)d_in[6];
    const float* wg    = (const float*)d_in[7];
    const float* bgp   = (const float*)d_in[8];

    float* out    = (float*)d_out;
    float* scores = out;                                  // [8,2048,2048]
    float* hidden = out + (size_t)BB * LL * LL;           // [8,2048,544]
    float* tdiff  = hidden + (size_t)BB * LL * HID;       // [8,2048,2048]

    float* pa  = (float*)d_ws;
    float* pbl = pa + BB * LL;
    float* ga5 = pbl + BB * LL;
    float* gb5 = ga5 + BB * LL;

    prep_k<<<BB * LL, 256, 0, stream>>>(etype, etime, wtpos, temb, wl, wg,
                                        blp, bgp, hidden, pa, pbl, ga5, gb5);
    pair_k<<<dim3(2, LL / 8, BB), 256, 0, stream>>>(etime, pa, pbl, ga5, gb5,
                                                    scores, tdiff);
}